// Round 7
// baseline (768.745 us; speedup 1.0000x reference)
//
#include <hip/hip_runtime.h>
#include <stdint.h>

#define S_LEN 2048
#define BATCH 2
#define NH 16
#define NKV 4
#define HD 128
#define HID 2048
#define MROWS (BATCH * S_LEN)  // 4096
#define PST 72                 // Pls row stride (u16): 144B = 9x16B -> 2-way bank alias (free)

typedef unsigned short u16;
typedef __attribute__((ext_vector_type(8))) short frag_ab;
typedef __attribute__((ext_vector_type(4))) float frag_cd;

static __device__ __forceinline__ float bf2f(u16 v) {
    union { unsigned u; float f; } t; t.u = ((unsigned)v) << 16; return t.f;
}
static __device__ __forceinline__ u16 f2bf(float f) {
    union { float f; unsigned u; } t; t.f = f;
    unsigned r = t.u + 0x7fffu + ((t.u >> 16) & 1u);  // RNE
    return (u16)(r >> 16);
}
// async global->LDS, 16B per lane; LDS dest = wave-uniform base + lane*16
static __device__ __forceinline__ void load_lds16(const u16* g, u16* l) {
    __builtin_amdgcn_global_load_lds((const __attribute__((address_space(1))) void*)g,
                                     (__attribute__((address_space(3))) void*)l, 16, 0, 0);
}

// ---------------- fp32 -> bf16 bulk convert ----------------
__global__ __launch_bounds__(256) void conv_f32_bf16(const float* __restrict__ src,
                                                     u16* __restrict__ dst, int n4) {
    int i = blockIdx.x * 256 + threadIdx.x;
    if (i >= n4) return;
    float4 v = ((const float4*)src)[i];
    ushort4 o;
    o.x = f2bf(v.x); o.y = f2bf(v.y); o.z = f2bf(v.z); o.w = f2bf(v.w);
    ((ushort4*)dst)[i] = o;
}

// ---------------- C = A (MxK) * B^T (B stored [N][K]), fp32 out ----------------
// 128x128 tile, 4 waves x (4x4) 16x16x32 MFMA, BK=32, global_load_lds width=16
// staging (m97 ladder step 3).
__global__ __launch_bounds__(256) void gemm_bt(const u16* __restrict__ A, const u16* __restrict__ B,
                                               float* __restrict__ C, int M, int N, int K) {
    __shared__ u16 As[128 * 32];
    __shared__ u16 Bs[128 * 32];
    const int tid = threadIdx.x;
    const int wave = tid >> 6, lane = tid & 63;
    const int quad = lane >> 4, lr = lane & 15;
    const int wm = (wave & 1) * 64, wn = (wave >> 1) * 64;
    const long bm = (long)blockIdx.x * 128, bn = (long)blockIdx.y * 128;
    // staging: chunk c = issue*256 + wave*64 + lane; row=c>>2, col16=c&3
    const int srow = (wave << 4) + (lane >> 2);   // + issue*64
    const int scol = (lane & 3) * 8;
    const u16* Ag = A + (bm + srow) * (long)K + scol;
    const u16* Bg = B + (bn + srow) * (long)K + scol;
    u16* AsW = As + wave * 512;                    // + issue*2048 (u16)
    u16* BsW = Bs + wave * 512;

    frag_cd acc[4][4];
#pragma unroll
    for (int i = 0; i < 4; i++)
#pragma unroll
        for (int j = 0; j < 4; j++) acc[i][j] = (frag_cd){0.f, 0.f, 0.f, 0.f};

    for (int k0 = 0; k0 < K; k0 += 32) {
        __syncthreads();  // prev iter's LDS readers done
        load_lds16(Ag + k0, AsW);
        load_lds16(Ag + (long)64 * K + k0, AsW + 2048);
        load_lds16(Bg + k0, BsW);
        load_lds16(Bg + (long)64 * K + k0, BsW + 2048);
        __syncthreads();  // staging complete (vmcnt(0) drained by barrier)
        frag_ab af[4], bfr[4];
#pragma unroll
        for (int i = 0; i < 4; i++) af[i] = *(const frag_ab*)(As + (wm + i * 16 + lr) * 32 + quad * 8);
#pragma unroll
        for (int j = 0; j < 4; j++) bfr[j] = *(const frag_ab*)(Bs + (wn + j * 16 + lr) * 32 + quad * 8);
#pragma unroll
        for (int i = 0; i < 4; i++)
#pragma unroll
            for (int j = 0; j < 4; j++)
                acc[i][j] = __builtin_amdgcn_mfma_f32_16x16x32_bf16(af[i], bfr[j], acc[i][j], 0, 0, 0);
    }
    // C/D layout: col = lane&15, row = (lane>>4)*4 + reg   [measured m89/m91]
#pragma unroll
    for (int i = 0; i < 4; i++)
#pragma unroll
        for (int j = 0; j < 4; j++)
#pragma unroll
            for (int r = 0; r < 4; r++) {
                long row = bm + wm + i * 16 + quad * 4 + r;
                long col = bn + wn + j * 16 + lr;
                C[row * N + col] = acc[i][j][r];
            }
}

// ---------------- RMSNorm(head_dim) + RoPE, fp32 in -> bf16 out [b][h][s][d] ----------------
__global__ __launch_bounds__(256) void rope_norm(const float* __restrict__ src, u16* __restrict__ dst,
                                                 const float* __restrict__ nw, int nh, int stride, int coff) {
    const int m = blockIdx.x;                 // 0..4095 (b*S+s)
    const int wave = threadIdx.x >> 6, lane = threadIdx.x & 63;
    const int s = m & (S_LEN - 1), b = m >> 11;
    const int d0 = 2 * lane;
    const float w0 = nw[d0], w1 = nw[d0 + 1];
    const int i0 = d0 & 63;
    const float lnt_over = 13.122363377404328f / 64.f;  // ln(500000)/64
    float inv0 = expf(-(float)i0 * lnt_over);
    float inv1 = expf(-(float)(i0 + 1) * lnt_over);
    float c0 = cosf((float)s * inv0), sn0 = sinf((float)s * inv0);
    float c1 = cosf((float)s * inv1), sn1 = sinf((float)s * inv1);
    for (int h = wave; h < nh; h += 4) {
        float2 x = *(const float2*)(src + (long)m * stride + coff + h * HD + d0);
        float ss = x.x * x.x + x.y * x.y;
#pragma unroll
        for (int off = 1; off < 64; off <<= 1) ss += __shfl_xor(ss, off);
        float rs = rsqrtf(ss * (1.f / HD) + 1e-5f);
        float xn0 = x.x * rs * w0;
        float xn1 = x.y * rs * w1;
        float p0 = __shfl_xor(xn0, 32);
        float p1 = __shfl_xor(xn1, 32);
        float r0 = (lane < 32) ? -p0 : p0;   // rotate_half
        float r1 = (lane < 32) ? -p1 : p1;
        float y0 = xn0 * c0 + r0 * sn0;
        float y1 = xn1 * c1 + r1 * sn1;
        unsigned outw = (unsigned)f2bf(y0) | ((unsigned)f2bf(y1) << 16);
        *(unsigned*)(dst + (((long)(b * nh + h) * S_LEN + s) * HD + d0)) = outw;
    }
}

// ---------------- V: fp32 gout [m][coff+kh*128+d] -> bf16 TRANSPOSED [b][kh][d][s] ----------------
__global__ __launch_bounds__(256) void pack_vt(const float* __restrict__ src, u16* __restrict__ dst,
                                               int stride, int coff) {
    __shared__ u16 t[128 * 72];  // [d][s], rows padded 64->72
    const int tid = threadIdx.x;
    const int st = blockIdx.x & 31;
    const int kh = (blockIdx.x >> 5) & 3;
    const int b = blockIdx.x >> 7;
    const long m0 = (long)b * S_LEN + st * 64;
#pragma unroll
    for (int c = 0; c < 8; c++) {
        int idx = c * 256 + tid;           // 0..2047 float4s
        int r = idx >> 5, cg = idx & 31;   // s-row 0..63, col-group 0..31
        float4 v = *(const float4*)(src + (m0 + r) * stride + coff + kh * HD + cg * 4);
        int col = cg * 4;
        t[(col + 0) * 72 + r] = f2bf(v.x);
        t[(col + 1) * 72 + r] = f2bf(v.y);
        t[(col + 2) * 72 + r] = f2bf(v.z);
        t[(col + 3) * 72 + r] = f2bf(v.w);
    }
    __syncthreads();
    const int d = tid >> 1, sh = (tid & 1) * 32;
    u16* dp = dst + ((long)(b * NKV + kh) * HD + d) * S_LEN + st * 64 + sh;
    const u16* tp = &t[d * 72 + sh];
    *(uint4*)(dp + 0)  = *(const uint4*)(tp + 0);
    *(uint4*)(dp + 8)  = *(const uint4*)(tp + 8);
    *(uint4*)(dp + 16) = *(const uint4*)(tp + 16);
    *(uint4*)(dp + 24) = *(const uint4*)(tp + 24);
}

// ---------------- MFMA flash attention v9: paired split-K (uniform blocks, full residency) ----------------
// v7 verified inner body + causal PAIRING of Q-tiles: block p handles tiles
// t1=63-p then t2=p. nkt(63-p)+nkt(p) == 33 for ALL p -> every block does
// exactly 33 kt. Grid = 32 pairs x 32 bh = 1024 blocks = EXACTLY 4 blocks/CU
// (VGPR<=128 via launch_bounds(256,4) -> 16 waves/CU; LDS 35840x4 = 143K),
// all resident, no refill, no tail (v8's 21.5% occupancy was the imbalance
// tail: 1..32 kt blocks, heavy chains defined makespan while CUs drained).
// Pls stride 72 (2-way bank alias = free, m136). No setprio/defer-max (v8
// bundle measured net-negative; reverted). XCD map unchanged: low 3 bits =
// (b,kh) -> each XCD re-reads one 1MB KV set (FETCH 12.4MB, verified v7/v8).
__global__ __launch_bounds__(256, 4) void flash_attn(const u16* __restrict__ Q, const u16* __restrict__ K,
                                                     const u16* __restrict__ Vt, u16* __restrict__ O) {
    __shared__ u16 Pls[4 * 32 * PST];       // 18432 B (per-wave P C->A round-trip)
    __shared__ float macc[2][8][16][16];    // 16384 B [mt][dt][col][row]
    __shared__ float mlb[4][2][16][2];      // 1024 B  [wave][mt][row][{m,l}]
    const int tid = threadIdx.x;
    const int wave = tid >> 6, lane = tid & 63;
    const int quad = lane >> 4, lr = lane & 15;
    const int g = blockIdx.x & 7;           // (b,kh) group -> XCD locality
    const int sub = (blockIdx.x >> 3) & 3;  // h within kv group
    const int p = blockIdx.x >> 5;          // pair index 0..31
    const int b = g >> 2, kh = g & 3;
    const int h = kh * 4 + sub;
    const float scale = 0.08838834764831845f;  // 1/sqrt(128)
    const u16* Qb = Q + ((long)(b * NH + h) * S_LEN) * HD;
    const u16* Kb = K + ((long)(b * NKV + kh) * S_LEN) * HD;
    const u16* Vb = Vt + ((long)(b * NKV + kh) * HD) * S_LEN;
    const int pbase = wave * 32 * PST;

    for (int ph = 0; ph < 2; ph++) {
        const int t = ph ? p : (63 - p);    // heavy tile first
        const int q0 = t * 32;
        const int nkt = (t >> 1) + 1;       // key tiles of 64 covering [0, 32t+32)

        frag_ab qf[2][4];
#pragma unroll
        for (int mt = 0; mt < 2; mt++) {
            int qrow = q0 + mt * 16 + lr;
#pragma unroll
            for (int ks = 0; ks < 4; ks++)
                qf[mt][ks] = *(const frag_ab*)(Qb + (long)qrow * HD + ks * 32 + quad * 8);
        }
        frag_cd oa[2][8];
        float m_i[2][4], l_i[2][4];
#pragma unroll
        for (int mt = 0; mt < 2; mt++) {
#pragma unroll
            for (int dt = 0; dt < 8; dt++) oa[mt][dt] = (frag_cd){0.f, 0.f, 0.f, 0.f};
#pragma unroll
            for (int r = 0; r < 4; r++) { m_i[mt][r] = -3e38f; l_i[mt][r] = 0.f; }
        }

        for (int kt = wave; kt < nkt; kt += 4) {
            const int j0 = kt * 64;
            // S = Q K^T  (kf direct from global K[key][d])
            frag_cd sa[2][4];
#pragma unroll
            for (int mt = 0; mt < 2; mt++)
#pragma unroll
                for (int nt = 0; nt < 4; nt++) sa[mt][nt] = (frag_cd){0.f, 0.f, 0.f, 0.f};
#pragma unroll
            for (int nt = 0; nt < 4; nt++) {
                frag_ab kf[4];
#pragma unroll
                for (int ks = 0; ks < 4; ks++)
                    kf[ks] = *(const frag_ab*)(Kb + (long)(j0 + nt * 16 + lr) * HD + ks * 32 + quad * 8);
#pragma unroll
                for (int mt = 0; mt < 2; mt++)
#pragma unroll
                    for (int ks = 0; ks < 4; ks++)
                        sa[mt][nt] = __builtin_amdgcn_mfma_f32_16x16x32_bf16(qf[mt][ks], kf[ks], sa[mt][nt], 0, 0, 0);
            }
            // early V fragment loads (hide latency under softmax)
            frag_ab vf[2][8];
#pragma unroll
            for (int ks = 0; ks < 2; ks++)
#pragma unroll
                for (int dt = 0; dt < 8; dt++)
                    vf[ks][dt] = *(const frag_ab*)(Vb + (long)(dt * 16 + lr) * S_LEN + j0 + ks * 32 + quad * 8);

            const bool need_mask = (j0 + 63) > q0;
            // online softmax (C-layout: row=quad*4+r, col=lr)
#pragma unroll
            for (int mt = 0; mt < 2; mt++) {
                float mrow[4] = {-3e38f, -3e38f, -3e38f, -3e38f};
#pragma unroll
                for (int nt = 0; nt < 4; nt++) {
                    int key = j0 + nt * 16 + lr;
#pragma unroll
                    for (int r = 0; r < 4; r++) {
                        int qrow = q0 + mt * 16 + quad * 4 + r;
                        float v = sa[mt][nt][r] * scale;
                        if (need_mask) v = (key <= qrow) ? v : -3e38f;
                        sa[mt][nt][r] = v;
                        mrow[r] = fmaxf(mrow[r], v);
                    }
                }
#pragma unroll
                for (int off = 1; off < 16; off <<= 1)
#pragma unroll
                    for (int r = 0; r < 4; r++) mrow[r] = fmaxf(mrow[r], __shfl_xor(mrow[r], off));
                float rs[4];
#pragma unroll
                for (int r = 0; r < 4; r++) {
                    float mn = fmaxf(m_i[mt][r], mrow[r]);
                    float alpha = __expf(m_i[mt][r] - mn);
                    m_i[mt][r] = mn;
                    l_i[mt][r] *= alpha;
                    rs[r] = 0.f;
#pragma unroll
                    for (int dt = 0; dt < 8; dt++) oa[mt][dt][r] *= alpha;
                }
#pragma unroll
                for (int nt = 0; nt < 4; nt++)
#pragma unroll
                    for (int r = 0; r < 4; r++) {
                        float pw = __expf(sa[mt][nt][r] - m_i[mt][r]);
                        rs[r] += pw;
                        Pls[pbase + (mt * 16 + quad * 4 + r) * PST + nt * 16 + lr] = f2bf(pw);
                    }
#pragma unroll
                for (int off = 1; off < 16; off <<= 1)
#pragma unroll
                    for (int r = 0; r < 4; r++) rs[r] += __shfl_xor(rs[r], off);
#pragma unroll
                for (int r = 0; r < 4; r++) l_i[mt][r] += rs[r];
            }

            // O += P V  (pf via per-wave LDS; vf pre-loaded)
#pragma unroll
            for (int ks = 0; ks < 2; ks++) {
                frag_ab pf[2];
#pragma unroll
                for (int mt = 0; mt < 2; mt++)
                    pf[mt] = *(const frag_ab*)&Pls[pbase + (mt * 16 + lr) * PST + ks * 32 + quad * 8];
#pragma unroll
                for (int dt = 0; dt < 8; dt++) {
                    oa[0][dt] = __builtin_amdgcn_mfma_f32_16x16x32_bf16(pf[0], vf[ks][dt], oa[0][dt], 0, 0, 0);
                    oa[1][dt] = __builtin_amdgcn_mfma_f32_16x16x32_bf16(pf[1], vf[ks][dt], oa[1][dt], 0, 0, 0);
                }
            }
        }

        // ---- flash-decoding merge across the 4 waves ----
        // publish per-wave (m, l); lanes lr==0 (one per quad) cover rows quad*4+r
        if (lr == 0) {
#pragma unroll
            for (int mt = 0; mt < 2; mt++)
#pragma unroll
                for (int r = 0; r < 4; r++) {
                    mlb[wave][mt][quad * 4 + r][0] = m_i[mt][r];
                    mlb[wave][mt][quad * 4 + r][1] = l_i[mt][r];
                }
        }
        __syncthreads();
        // global max + merged denom; rescale own accumulator in-reg
        float inv[2][4];
#pragma unroll
        for (int mt = 0; mt < 2; mt++)
#pragma unroll
            for (int r = 0; r < 4; r++) {
                int row = quad * 4 + r;
                float m0 = mlb[0][mt][row][0], m1 = mlb[1][mt][row][0];
                float m2 = mlb[2][mt][row][0], m3 = mlb[3][mt][row][0];
                float ms = fmaxf(fmaxf(m0, m1), fmaxf(m2, m3));
                float ls = mlb[0][mt][row][1] * __expf(m0 - ms) + mlb[1][mt][row][1] * __expf(m1 - ms)
                         + mlb[2][mt][row][1] * __expf(m2 - ms) + mlb[3][mt][row][1] * __expf(m3 - ms);
                inv[mt][r] = 1.f / ls;
                float alpha = __expf(m_i[mt][r] - ms);   // 0 for waves with no work
#pragma unroll
                for (int dt = 0; dt < 8; dt++) oa[mt][dt][r] *= alpha;
            }
        // serialized accumulate into macc (float4 rows: [mt][dt][col=lr][row quad*4..+3])
        for (int w = 0; w < 4; w++) {
            if (wave == w) {
#pragma unroll
                for (int mt = 0; mt < 2; mt++)
#pragma unroll
                    for (int dt = 0; dt < 8; dt++) {
                        frag_cd* pp = (frag_cd*)&macc[mt][dt][lr][quad * 4];
                        if (w == 0) *pp = oa[mt][dt];
                        else {
                            frag_cd o = *pp;
#pragma unroll
                            for (int r = 0; r < 4; r++) o[r] += oa[mt][dt][r];
                            *pp = o;
                        }
                    }
            }
            __syncthreads();
        }
        // cooperative epilogue: wave handles dt = 2*wave, 2*wave+1
#pragma unroll
        for (int mt = 0; mt < 2; mt++)
#pragma unroll
            for (int dto = 0; dto < 2; dto++) {
                int dt = wave * 2 + dto;
                frag_cd v = *(const frag_cd*)&macc[mt][dt][lr][quad * 4];
#pragma unroll
                for (int r = 0; r < 4; r++) {
                    int s = q0 + mt * 16 + quad * 4 + r;
                    O[((long)b * S_LEN + s) * (NH * HD) + h * HD + dt * 16 + lr] =
                        f2bf(v[r] * inv[mt][r]);
                }
            }
    }
}

extern "C" void kernel_launch(void* const* d_in, const int* in_sizes, int n_in,
                              void* d_out, int out_size, void* d_ws, size_t ws_size,
                              hipStream_t stream) {
    const float* hs  = (const float*)d_in[0];
    const float* q_w = (const float*)d_in[1];
    const float* k_w = (const float*)d_in[2];
    const float* v_w = (const float*)d_in[3];
    const float* o_w = (const float*)d_in[4];
    const float* qnw = (const float*)d_in[5];
    const float* knw = (const float*)d_in[6];
    float* out = (float*)d_out;

    // Workspace (72 MiB, live ranges stream-serialized & disjoint):
    //   [ 0,16M) hs_bf : hidden bf16; later attn-out bf16
    //   [16,24M) wbuf  : weights bf16 (Q 8M; then KV 4M; then O 8M)
    //   [24,56M) gout  : fp32 GEMM out (Q all 32M; KV uses [24,40) only)
    //   [40,44M) Kr    : bf16 [b][4][s][128]
    //   [44,48M) Vt    : bf16 [b][4][d][s] transposed
    //   [56,72M) Qr    : bf16 [b][16][s][128]
    char* ws = (char*)d_ws;
    u16* hs_bf  = (u16*)(ws);
    u16* wbuf   = (u16*)(ws + (16ul << 20));
    float* gout = (float*)(ws + (24ul << 20));
    u16* Kr     = (u16*)(ws + (40ul << 20));
    u16* Vt     = (u16*)(ws + (44ul << 20));
    u16* Qr     = (u16*)(ws + (56ul << 20));
    (void)ws_size; (void)in_sizes; (void)n_in; (void)out_size;

    // hidden -> bf16
    conv_f32_bf16<<<(MROWS * HID / 4 + 255) / 256, 256, 0, stream>>>(hs, hs_bf, MROWS * HID / 4);

    // Q = hs @ q_w^T ; rmsnorm + rope
    conv_f32_bf16<<<(HID * HID / 4 + 255) / 256, 256, 0, stream>>>(q_w, wbuf, HID * HID / 4);
    dim3 gq(MROWS / 128, HID / 128);
    gemm_bt<<<gq, 256, 0, stream>>>(hs_bf, wbuf, gout, MROWS, HID, HID);
    rope_norm<<<MROWS, 256, 0, stream>>>(gout, Qr, qnw, NH, HID, 0);

    // K|V fused projection: wbuf rows [0,512)=k_w, [512,1024)=v_w; N=1024
    conv_f32_bf16<<<(NKV * HD * HID / 4 + 255) / 256, 256, 0, stream>>>(k_w, wbuf, NKV * HD * HID / 4);
    conv_f32_bf16<<<(NKV * HD * HID / 4 + 255) / 256, 256, 0, stream>>>(v_w, wbuf + NKV * HD * HID, NKV * HD * HID / 4);
    dim3 gkv(MROWS / 128, (2 * NKV * HD) / 128);
    gemm_bt<<<gkv, 256, 0, stream>>>(hs_bf, wbuf, gout, MROWS, 2 * NKV * HD, HID);
    rope_norm<<<MROWS, 256, 0, stream>>>(gout, Kr, knw, NKV, 2 * NKV * HD, 0);
    pack_vt<<<BATCH * NKV * (S_LEN / 64), 256, 0, stream>>>(gout, Vt, 2 * NKV * HD, NKV * HD);

    // attention -> hs_bf  (grid = 32 pairs x 32 bh = 1024, paired split-K blocks)
    flash_attn<<<1024, 256, 0, stream>>>(Qr, Kr, Vt, hs_bf);

    // out = attn @ o_w^T
    conv_f32_bf16<<<(HID * HID / 4 + 255) / 256, 256, 0, stream>>>(o_w, wbuf, HID * HID / 4);
    gemm_bt<<<gq, 256, 0, stream>>>(hs_bf, wbuf, out, MROWS, HID, HID);
}

// Round 8
// 462.904 us; speedup vs baseline: 1.6607x; 1.6607x over previous
//
#include <hip/hip_runtime.h>
#include <stdint.h>

#define S_LEN 2048
#define BATCH 2
#define NH 16
#define NKV 4
#define HD 128
#define HID 2048
#define MROWS (BATCH * S_LEN)  // 4096
#define PST 72                 // Pls row stride (u16): 144B = 9x16B -> 2-way bank alias (free)

typedef unsigned short u16;
typedef __attribute__((ext_vector_type(8))) short frag_ab;
typedef __attribute__((ext_vector_type(4))) float frag_cd;

static __device__ __forceinline__ float bf2f(u16 v) {
    union { unsigned u; float f; } t; t.u = ((unsigned)v) << 16; return t.f;
}
static __device__ __forceinline__ u16 f2bf(float f) {
    union { float f; unsigned u; } t; t.f = f;
    unsigned r = t.u + 0x7fffu + ((t.u >> 16) & 1u);  // RNE
    return (u16)(r >> 16);
}
// async global->LDS, 16B per lane; LDS dest = wave-uniform base + lane*16
static __device__ __forceinline__ void load_lds16(const u16* g, u16* l) {
    __builtin_amdgcn_global_load_lds((const __attribute__((address_space(1))) void*)g,
                                     (__attribute__((address_space(3))) void*)l, 16, 0, 0);
}

// ---------------- fp32 -> bf16 bulk convert ----------------
__global__ __launch_bounds__(256) void conv_f32_bf16(const float* __restrict__ src,
                                                     u16* __restrict__ dst, int n4) {
    int i = blockIdx.x * 256 + threadIdx.x;
    if (i >= n4) return;
    float4 v = ((const float4*)src)[i];
    ushort4 o;
    o.x = f2bf(v.x); o.y = f2bf(v.y); o.z = f2bf(v.z); o.w = f2bf(v.w);
    ((ushort4*)dst)[i] = o;
}

// ---------------- C = A (MxK) * B^T (B stored [N][K]), fp32 out ----------------
// 128x128 tile, 4 waves x (4x4) 16x16x32 MFMA, BK=32, global_load_lds width=16
// staging (m97 ladder step 3).
__global__ __launch_bounds__(256) void gemm_bt(const u16* __restrict__ A, const u16* __restrict__ B,
                                               float* __restrict__ C, int M, int N, int K) {
    __shared__ u16 As[128 * 32];
    __shared__ u16 Bs[128 * 32];
    const int tid = threadIdx.x;
    const int wave = tid >> 6, lane = tid & 63;
    const int quad = lane >> 4, lr = lane & 15;
    const int wm = (wave & 1) * 64, wn = (wave >> 1) * 64;
    const long bm = (long)blockIdx.x * 128, bn = (long)blockIdx.y * 128;
    // staging: chunk c = issue*256 + wave*64 + lane; row=c>>2, col16=c&3
    const int srow = (wave << 4) + (lane >> 2);   // + issue*64
    const int scol = (lane & 3) * 8;
    const u16* Ag = A + (bm + srow) * (long)K + scol;
    const u16* Bg = B + (bn + srow) * (long)K + scol;
    u16* AsW = As + wave * 512;                    // + issue*2048 (u16)
    u16* BsW = Bs + wave * 512;

    frag_cd acc[4][4];
#pragma unroll
    for (int i = 0; i < 4; i++)
#pragma unroll
        for (int j = 0; j < 4; j++) acc[i][j] = (frag_cd){0.f, 0.f, 0.f, 0.f};

    for (int k0 = 0; k0 < K; k0 += 32) {
        __syncthreads();  // prev iter's LDS readers done
        load_lds16(Ag + k0, AsW);
        load_lds16(Ag + (long)64 * K + k0, AsW + 2048);
        load_lds16(Bg + k0, BsW);
        load_lds16(Bg + (long)64 * K + k0, BsW + 2048);
        __syncthreads();  // staging complete (vmcnt(0) drained by barrier)
        frag_ab af[4], bfr[4];
#pragma unroll
        for (int i = 0; i < 4; i++) af[i] = *(const frag_ab*)(As + (wm + i * 16 + lr) * 32 + quad * 8);
#pragma unroll
        for (int j = 0; j < 4; j++) bfr[j] = *(const frag_ab*)(Bs + (wn + j * 16 + lr) * 32 + quad * 8);
#pragma unroll
        for (int i = 0; i < 4; i++)
#pragma unroll
            for (int j = 0; j < 4; j++)
                acc[i][j] = __builtin_amdgcn_mfma_f32_16x16x32_bf16(af[i], bfr[j], acc[i][j], 0, 0, 0);
    }
    // C/D layout: col = lane&15, row = (lane>>4)*4 + reg   [measured m89/m91]
#pragma unroll
    for (int i = 0; i < 4; i++)
#pragma unroll
        for (int j = 0; j < 4; j++)
#pragma unroll
            for (int r = 0; r < 4; r++) {
                long row = bm + wm + i * 16 + quad * 4 + r;
                long col = bn + wn + j * 16 + lr;
                C[row * N + col] = acc[i][j][r];
            }
}

// ---------------- RMSNorm(head_dim) + RoPE, fp32 in -> bf16 out [b][h][s][d] ----------------
__global__ __launch_bounds__(256) void rope_norm(const float* __restrict__ src, u16* __restrict__ dst,
                                                 const float* __restrict__ nw, int nh, int stride, int coff) {
    const int m = blockIdx.x;                 // 0..4095 (b*S+s)
    const int wave = threadIdx.x >> 6, lane = threadIdx.x & 63;
    const int s = m & (S_LEN - 1), b = m >> 11;
    const int d0 = 2 * lane;
    const float w0 = nw[d0], w1 = nw[d0 + 1];
    const int i0 = d0 & 63;
    const float lnt_over = 13.122363377404328f / 64.f;  // ln(500000)/64
    float inv0 = expf(-(float)i0 * lnt_over);
    float inv1 = expf(-(float)(i0 + 1) * lnt_over);
    float c0 = cosf((float)s * inv0), sn0 = sinf((float)s * inv0);
    float c1 = cosf((float)s * inv1), sn1 = sinf((float)s * inv1);
    for (int h = wave; h < nh; h += 4) {
        float2 x = *(const float2*)(src + (long)m * stride + coff + h * HD + d0);
        float ss = x.x * x.x + x.y * x.y;
#pragma unroll
        for (int off = 1; off < 64; off <<= 1) ss += __shfl_xor(ss, off);
        float rs = rsqrtf(ss * (1.f / HD) + 1e-5f);
        float xn0 = x.x * rs * w0;
        float xn1 = x.y * rs * w1;
        float p0 = __shfl_xor(xn0, 32);
        float p1 = __shfl_xor(xn1, 32);
        float r0 = (lane < 32) ? -p0 : p0;   // rotate_half
        float r1 = (lane < 32) ? -p1 : p1;
        float y0 = xn0 * c0 + r0 * sn0;
        float y1 = xn1 * c1 + r1 * sn1;
        unsigned outw = (unsigned)f2bf(y0) | ((unsigned)f2bf(y1) << 16);
        *(unsigned*)(dst + (((long)(b * nh + h) * S_LEN + s) * HD + d0)) = outw;
    }
}

// ---------------- V: fp32 gout [m][coff+kh*128+d] -> bf16 TRANSPOSED [b][kh][d][s] ----------------
__global__ __launch_bounds__(256) void pack_vt(const float* __restrict__ src, u16* __restrict__ dst,
                                               int stride, int coff) {
    __shared__ u16 t[128 * 72];  // [d][s], rows padded 64->72
    const int tid = threadIdx.x;
    const int st = blockIdx.x & 31;
    const int kh = (blockIdx.x >> 5) & 3;
    const int b = blockIdx.x >> 7;
    const long m0 = (long)b * S_LEN + st * 64;
#pragma unroll
    for (int c = 0; c < 8; c++) {
        int idx = c * 256 + tid;           // 0..2047 float4s
        int r = idx >> 5, cg = idx & 31;   // s-row 0..63, col-group 0..31
        float4 v = *(const float4*)(src + (m0 + r) * stride + coff + kh * HD + cg * 4);
        int col = cg * 4;
        t[(col + 0) * 72 + r] = f2bf(v.x);
        t[(col + 1) * 72 + r] = f2bf(v.y);
        t[(col + 2) * 72 + r] = f2bf(v.z);
        t[(col + 3) * 72 + r] = f2bf(v.w);
    }
    __syncthreads();
    const int d = tid >> 1, sh = (tid & 1) * 32;
    u16* dp = dst + ((long)(b * NKV + kh) * HD + d) * S_LEN + st * 64 + sh;
    const u16* tp = &t[d * 72 + sh];
    *(uint4*)(dp + 0)  = *(const uint4*)(tp + 0);
    *(uint4*)(dp + 8)  = *(const uint4*)(tp + 8);
    *(uint4*)(dp + 16) = *(const uint4*)(tp + 16);
    *(uint4*)(dp + 24) = *(const uint4*)(tp + 24);
}

// ---------------- MFMA flash attention v10: paired split-K, natural regalloc ----------------
// v9's pairing (block p: tiles 63-p then p; nkt sums to exactly 33 kt for all
// p -> 1024 uniform blocks = 4/CU, no refill, no tail) with v7/v8's
// launch_bounds(256,2): allocator naturally picks 128 VGPR (measured v7/v8,
// zero spills) which ALREADY permits 4 waves/SIMD. v9's (256,4) forced
// VGPR=64 -> 1.1GB scratch spill traffic -> 475us (3rd confirmation: never
// coerce occupancy via min-waves on this body; v4 and v9 both failed this way).
// Pls stride 72 (2-way bank alias = free). XCD map: low 3 bits = (b,kh).
__global__ __launch_bounds__(256, 2) void flash_attn(const u16* __restrict__ Q, const u16* __restrict__ K,
                                                     const u16* __restrict__ Vt, u16* __restrict__ O) {
    __shared__ u16 Pls[4 * 32 * PST];       // 18432 B (per-wave P C->A round-trip)
    __shared__ float macc[2][8][16][16];    // 16384 B [mt][dt][col][row]
    __shared__ float mlb[4][2][16][2];      // 1024 B  [wave][mt][row][{m,l}]
    const int tid = threadIdx.x;
    const int wave = tid >> 6, lane = tid & 63;
    const int quad = lane >> 4, lr = lane & 15;
    const int g = blockIdx.x & 7;           // (b,kh) group -> XCD locality
    const int sub = (blockIdx.x >> 3) & 3;  // h within kv group
    const int p = blockIdx.x >> 5;          // pair index 0..31
    const int b = g >> 2, kh = g & 3;
    const int h = kh * 4 + sub;
    const float scale = 0.08838834764831845f;  // 1/sqrt(128)
    const u16* Qb = Q + ((long)(b * NH + h) * S_LEN) * HD;
    const u16* Kb = K + ((long)(b * NKV + kh) * S_LEN) * HD;
    const u16* Vb = Vt + ((long)(b * NKV + kh) * HD) * S_LEN;
    const int pbase = wave * 32 * PST;

    for (int ph = 0; ph < 2; ph++) {
        const int t = ph ? p : (63 - p);    // heavy tile first
        const int q0 = t * 32;
        const int nkt = (t >> 1) + 1;       // key tiles of 64 covering [0, 32t+32)

        frag_ab qf[2][4];
#pragma unroll
        for (int mt = 0; mt < 2; mt++) {
            int qrow = q0 + mt * 16 + lr;
#pragma unroll
            for (int ks = 0; ks < 4; ks++)
                qf[mt][ks] = *(const frag_ab*)(Qb + (long)qrow * HD + ks * 32 + quad * 8);
        }
        frag_cd oa[2][8];
        float m_i[2][4], l_i[2][4];
#pragma unroll
        for (int mt = 0; mt < 2; mt++) {
#pragma unroll
            for (int dt = 0; dt < 8; dt++) oa[mt][dt] = (frag_cd){0.f, 0.f, 0.f, 0.f};
#pragma unroll
            for (int r = 0; r < 4; r++) { m_i[mt][r] = -3e38f; l_i[mt][r] = 0.f; }
        }

        for (int kt = wave; kt < nkt; kt += 4) {
            const int j0 = kt * 64;
            // S = Q K^T  (kf direct from global K[key][d])
            frag_cd sa[2][4];
#pragma unroll
            for (int mt = 0; mt < 2; mt++)
#pragma unroll
                for (int nt = 0; nt < 4; nt++) sa[mt][nt] = (frag_cd){0.f, 0.f, 0.f, 0.f};
#pragma unroll
            for (int nt = 0; nt < 4; nt++) {
                frag_ab kf[4];
#pragma unroll
                for (int ks = 0; ks < 4; ks++)
                    kf[ks] = *(const frag_ab*)(Kb + (long)(j0 + nt * 16 + lr) * HD + ks * 32 + quad * 8);
#pragma unroll
                for (int mt = 0; mt < 2; mt++)
#pragma unroll
                    for (int ks = 0; ks < 4; ks++)
                        sa[mt][nt] = __builtin_amdgcn_mfma_f32_16x16x32_bf16(qf[mt][ks], kf[ks], sa[mt][nt], 0, 0, 0);
            }
            // early V fragment loads (hide latency under softmax)
            frag_ab vf[2][8];
#pragma unroll
            for (int ks = 0; ks < 2; ks++)
#pragma unroll
                for (int dt = 0; dt < 8; dt++)
                    vf[ks][dt] = *(const frag_ab*)(Vb + (long)(dt * 16 + lr) * S_LEN + j0 + ks * 32 + quad * 8);

            const bool need_mask = (j0 + 63) > q0;
            // online softmax (C-layout: row=quad*4+r, col=lr)
#pragma unroll
            for (int mt = 0; mt < 2; mt++) {
                float mrow[4] = {-3e38f, -3e38f, -3e38f, -3e38f};
#pragma unroll
                for (int nt = 0; nt < 4; nt++) {
                    int key = j0 + nt * 16 + lr;
#pragma unroll
                    for (int r = 0; r < 4; r++) {
                        int qrow = q0 + mt * 16 + quad * 4 + r;
                        float v = sa[mt][nt][r] * scale;
                        if (need_mask) v = (key <= qrow) ? v : -3e38f;
                        sa[mt][nt][r] = v;
                        mrow[r] = fmaxf(mrow[r], v);
                    }
                }
#pragma unroll
                for (int off = 1; off < 16; off <<= 1)
#pragma unroll
                    for (int r = 0; r < 4; r++) mrow[r] = fmaxf(mrow[r], __shfl_xor(mrow[r], off));
                float rs[4];
#pragma unroll
                for (int r = 0; r < 4; r++) {
                    float mn = fmaxf(m_i[mt][r], mrow[r]);
                    float alpha = __expf(m_i[mt][r] - mn);
                    m_i[mt][r] = mn;
                    l_i[mt][r] *= alpha;
                    rs[r] = 0.f;
#pragma unroll
                    for (int dt = 0; dt < 8; dt++) oa[mt][dt][r] *= alpha;
                }
#pragma unroll
                for (int nt = 0; nt < 4; nt++)
#pragma unroll
                    for (int r = 0; r < 4; r++) {
                        float pw = __expf(sa[mt][nt][r] - m_i[mt][r]);
                        rs[r] += pw;
                        Pls[pbase + (mt * 16 + quad * 4 + r) * PST + nt * 16 + lr] = f2bf(pw);
                    }
#pragma unroll
                for (int off = 1; off < 16; off <<= 1)
#pragma unroll
                    for (int r = 0; r < 4; r++) rs[r] += __shfl_xor(rs[r], off);
#pragma unroll
                for (int r = 0; r < 4; r++) l_i[mt][r] += rs[r];
            }

            // O += P V  (pf via per-wave LDS; vf pre-loaded)
#pragma unroll
            for (int ks = 0; ks < 2; ks++) {
                frag_ab pf[2];
#pragma unroll
                for (int mt = 0; mt < 2; mt++)
                    pf[mt] = *(const frag_ab*)&Pls[pbase + (mt * 16 + lr) * PST + ks * 32 + quad * 8];
#pragma unroll
                for (int dt = 0; dt < 8; dt++) {
                    oa[0][dt] = __builtin_amdgcn_mfma_f32_16x16x32_bf16(pf[0], vf[ks][dt], oa[0][dt], 0, 0, 0);
                    oa[1][dt] = __builtin_amdgcn_mfma_f32_16x16x32_bf16(pf[1], vf[ks][dt], oa[1][dt], 0, 0, 0);
                }
            }
        }

        // ---- flash-decoding merge across the 4 waves ----
        // publish per-wave (m, l); lanes lr==0 (one per quad) cover rows quad*4+r
        if (lr == 0) {
#pragma unroll
            for (int mt = 0; mt < 2; mt++)
#pragma unroll
                for (int r = 0; r < 4; r++) {
                    mlb[wave][mt][quad * 4 + r][0] = m_i[mt][r];
                    mlb[wave][mt][quad * 4 + r][1] = l_i[mt][r];
                }
        }
        __syncthreads();
        // global max + merged denom; rescale own accumulator in-reg
        float inv[2][4];
#pragma unroll
        for (int mt = 0; mt < 2; mt++)
#pragma unroll
            for (int r = 0; r < 4; r++) {
                int row = quad * 4 + r;
                float m0 = mlb[0][mt][row][0], m1 = mlb[1][mt][row][0];
                float m2 = mlb[2][mt][row][0], m3 = mlb[3][mt][row][0];
                float ms = fmaxf(fmaxf(m0, m1), fmaxf(m2, m3));
                float ls = mlb[0][mt][row][1] * __expf(m0 - ms) + mlb[1][mt][row][1] * __expf(m1 - ms)
                         + mlb[2][mt][row][1] * __expf(m2 - ms) + mlb[3][mt][row][1] * __expf(m3 - ms);
                inv[mt][r] = 1.f / ls;
                float alpha = __expf(m_i[mt][r] - ms);   // 0 for waves with no work
#pragma unroll
                for (int dt = 0; dt < 8; dt++) oa[mt][dt][r] *= alpha;
            }
        // serialized accumulate into macc (float4 rows: [mt][dt][col=lr][row quad*4..+3])
        for (int w = 0; w < 4; w++) {
            if (wave == w) {
#pragma unroll
                for (int mt = 0; mt < 2; mt++)
#pragma unroll
                    for (int dt = 0; dt < 8; dt++) {
                        frag_cd* pp = (frag_cd*)&macc[mt][dt][lr][quad * 4];
                        if (w == 0) *pp = oa[mt][dt];
                        else {
                            frag_cd o = *pp;
#pragma unroll
                            for (int r = 0; r < 4; r++) o[r] += oa[mt][dt][r];
                            *pp = o;
                        }
                    }
            }
            __syncthreads();
        }
        // cooperative epilogue: wave handles dt = 2*wave, 2*wave+1
#pragma unroll
        for (int mt = 0; mt < 2; mt++)
#pragma unroll
            for (int dto = 0; dto < 2; dto++) {
                int dt = wave * 2 + dto;
                frag_cd v = *(const frag_cd*)&macc[mt][dt][lr][quad * 4];
#pragma unroll
                for (int r = 0; r < 4; r++) {
                    int s = q0 + mt * 16 + quad * 4 + r;
                    O[((long)b * S_LEN + s) * (NH * HD) + h * HD + dt * 16 + lr] =
                        f2bf(v[r] * inv[mt][r]);
                }
            }
    }
}

extern "C" void kernel_launch(void* const* d_in, const int* in_sizes, int n_in,
                              void* d_out, int out_size, void* d_ws, size_t ws_size,
                              hipStream_t stream) {
    const float* hs  = (const float*)d_in[0];
    const float* q_w = (const float*)d_in[1];
    const float* k_w = (const float*)d_in[2];
    const float* v_w = (const float*)d_in[3];
    const float* o_w = (const float*)d_in[4];
    const float* qnw = (const float*)d_in[5];
    const float* knw = (const float*)d_in[6];
    float* out = (float*)d_out;

    // Workspace (72 MiB, live ranges stream-serialized & disjoint):
    //   [ 0,16M) hs_bf : hidden bf16; later attn-out bf16
    //   [16,24M) wbuf  : weights bf16 (Q 8M; then KV 4M; then O 8M)
    //   [24,56M) gout  : fp32 GEMM out (Q all 32M; KV uses [24,40) only)
    //   [40,44M) Kr    : bf16 [b][4][s][128]
    //   [44,48M) Vt    : bf16 [b][4][d][s] transposed
    //   [56,72M) Qr    : bf16 [b][16][s][128]
    char* ws = (char*)d_ws;
    u16* hs_bf  = (u16*)(ws);
    u16* wbuf   = (u16*)(ws + (16ul << 20));
    float* gout = (float*)(ws + (24ul << 20));
    u16* Kr     = (u16*)(ws + (40ul << 20));
    u16* Vt     = (u16*)(ws + (44ul << 20));
    u16* Qr     = (u16*)(ws + (56ul << 20));
    (void)ws_size; (void)in_sizes; (void)n_in; (void)out_size;

    // hidden -> bf16
    conv_f32_bf16<<<(MROWS * HID / 4 + 255) / 256, 256, 0, stream>>>(hs, hs_bf, MROWS * HID / 4);

    // Q = hs @ q_w^T ; rmsnorm + rope
    conv_f32_bf16<<<(HID * HID / 4 + 255) / 256, 256, 0, stream>>>(q_w, wbuf, HID * HID / 4);
    dim3 gq(MROWS / 128, HID / 128);
    gemm_bt<<<gq, 256, 0, stream>>>(hs_bf, wbuf, gout, MROWS, HID, HID);
    rope_norm<<<MROWS, 256, 0, stream>>>(gout, Qr, qnw, NH, HID, 0);

    // K|V fused projection: wbuf rows [0,512)=k_w, [512,1024)=v_w; N=1024
    conv_f32_bf16<<<(NKV * HD * HID / 4 + 255) / 256, 256, 0, stream>>>(k_w, wbuf, NKV * HD * HID / 4);
    conv_f32_bf16<<<(NKV * HD * HID / 4 + 255) / 256, 256, 0, stream>>>(v_w, wbuf + NKV * HD * HID, NKV * HD * HID / 4);
    dim3 gkv(MROWS / 128, (2 * NKV * HD) / 128);
    gemm_bt<<<gkv, 256, 0, stream>>>(hs_bf, wbuf, gout, MROWS, 2 * NKV * HD, HID);
    rope_norm<<<MROWS, 256, 0, stream>>>(gout, Kr, knw, NKV, 2 * NKV * HD, 0);
    pack_vt<<<BATCH * NKV * (S_LEN / 64), 256, 0, stream>>>(gout, Vt, 2 * NKV * HD, NKV * HD);

    // attention -> hs_bf  (grid = 32 pairs x 32 bh = 1024, paired split-K blocks)
    flash_attn<<<1024, 256, 0, stream>>>(Qr, Kr, Vt, hs_bf);

    // out = attn @ o_w^T
    conv_f32_bf16<<<(HID * HID / 4 + 255) / 256, 256, 0, stream>>>(o_w, wbuf, HID * HID / 4);
    gemm_bt<<<gq, 256, 0, stream>>>(hs_bf, wbuf, out, MROWS, HID, HID);
}

// Round 9
// 448.439 us; speedup vs baseline: 1.7143x; 1.0323x over previous
//
#include <hip/hip_runtime.h>
#include <stdint.h>

#define S_LEN 2048
#define BATCH 2
#define NH 16
#define NKV 4
#define HD 128
#define HID 2048
#define MROWS (BATCH * S_LEN)  // 4096
#define PST 72                 // Pls row stride (u16): 144B = 9x16B -> 2-way bank alias (free)

typedef unsigned short u16;
typedef __attribute__((ext_vector_type(8))) short frag_ab;
typedef __attribute__((ext_vector_type(4))) float frag_cd;

static __device__ __forceinline__ float bf2f(u16 v) {
    union { unsigned u; float f; } t; t.u = ((unsigned)v) << 16; return t.f;
}
static __device__ __forceinline__ u16 f2bf(float f) {
    union { float f; unsigned u; } t; t.f = f;
    unsigned r = t.u + 0x7fffu + ((t.u >> 16) & 1u);  // RNE
    return (u16)(r >> 16);
}
// async global->LDS, 16B per lane; LDS dest = wave-uniform base + lane*16
static __device__ __forceinline__ void load_lds16(const u16* g, u16* l) {
    __builtin_amdgcn_global_load_lds((const __attribute__((address_space(1))) void*)g,
                                     (__attribute__((address_space(3))) void*)l, 16, 0, 0);
}

// ---------------- fp32 -> bf16 bulk convert ----------------
__global__ __launch_bounds__(256) void conv_f32_bf16(const float* __restrict__ src,
                                                     u16* __restrict__ dst, int n4) {
    int i = blockIdx.x * 256 + threadIdx.x;
    if (i >= n4) return;
    float4 v = ((const float4*)src)[i];
    ushort4 o;
    o.x = f2bf(v.x); o.y = f2bf(v.y); o.z = f2bf(v.z); o.w = f2bf(v.w);
    ((ushort4*)dst)[i] = o;
}

// ---------------- C = A (MxK) * B^T (B stored [N][K]), fp32 out ----------------
// 128x128 tile, 4 waves x (4x4) 16x16x32 MFMA, BK=32, global_load_lds width=16
// staging (m97 ladder step 3).
__global__ __launch_bounds__(256) void gemm_bt(const u16* __restrict__ A, const u16* __restrict__ B,
                                               float* __restrict__ C, int M, int N, int K) {
    __shared__ u16 As[128 * 32];
    __shared__ u16 Bs[128 * 32];
    const int tid = threadIdx.x;
    const int wave = tid >> 6, lane = tid & 63;
    const int quad = lane >> 4, lr = lane & 15;
    const int wm = (wave & 1) * 64, wn = (wave >> 1) * 64;
    const long bm = (long)blockIdx.x * 128, bn = (long)blockIdx.y * 128;
    // staging: chunk c = issue*256 + wave*64 + lane; row=c>>2, col16=c&3
    const int srow = (wave << 4) + (lane >> 2);   // + issue*64
    const int scol = (lane & 3) * 8;
    const u16* Ag = A + (bm + srow) * (long)K + scol;
    const u16* Bg = B + (bn + srow) * (long)K + scol;
    u16* AsW = As + wave * 512;                    // + issue*2048 (u16)
    u16* BsW = Bs + wave * 512;

    frag_cd acc[4][4];
#pragma unroll
    for (int i = 0; i < 4; i++)
#pragma unroll
        for (int j = 0; j < 4; j++) acc[i][j] = (frag_cd){0.f, 0.f, 0.f, 0.f};

    for (int k0 = 0; k0 < K; k0 += 32) {
        __syncthreads();  // prev iter's LDS readers done
        load_lds16(Ag + k0, AsW);
        load_lds16(Ag + (long)64 * K + k0, AsW + 2048);
        load_lds16(Bg + k0, BsW);
        load_lds16(Bg + (long)64 * K + k0, BsW + 2048);
        __syncthreads();  // staging complete (vmcnt(0) drained by barrier)
        frag_ab af[4], bfr[4];
#pragma unroll
        for (int i = 0; i < 4; i++) af[i] = *(const frag_ab*)(As + (wm + i * 16 + lr) * 32 + quad * 8);
#pragma unroll
        for (int j = 0; j < 4; j++) bfr[j] = *(const frag_ab*)(Bs + (wn + j * 16 + lr) * 32 + quad * 8);
#pragma unroll
        for (int i = 0; i < 4; i++)
#pragma unroll
            for (int j = 0; j < 4; j++)
                acc[i][j] = __builtin_amdgcn_mfma_f32_16x16x32_bf16(af[i], bfr[j], acc[i][j], 0, 0, 0);
    }
    // C/D layout: col = lane&15, row = (lane>>4)*4 + reg   [measured m89/m91]
#pragma unroll
    for (int i = 0; i < 4; i++)
#pragma unroll
        for (int j = 0; j < 4; j++)
#pragma unroll
            for (int r = 0; r < 4; r++) {
                long row = bm + wm + i * 16 + quad * 4 + r;
                long col = bn + wn + j * 16 + lr;
                C[row * N + col] = acc[i][j][r];
            }
}

// ---------------- RMSNorm(head_dim) + RoPE, fp32 in -> bf16 out [b][h][s][d] ----------------
__global__ __launch_bounds__(256) void rope_norm(const float* __restrict__ src, u16* __restrict__ dst,
                                                 const float* __restrict__ nw, int nh, int stride, int coff) {
    const int m = blockIdx.x;                 // 0..4095 (b*S+s)
    const int wave = threadIdx.x >> 6, lane = threadIdx.x & 63;
    const int s = m & (S_LEN - 1), b = m >> 11;
    const int d0 = 2 * lane;
    const float w0 = nw[d0], w1 = nw[d0 + 1];
    const int i0 = d0 & 63;
    const float lnt_over = 13.122363377404328f / 64.f;  // ln(500000)/64
    float inv0 = expf(-(float)i0 * lnt_over);
    float inv1 = expf(-(float)(i0 + 1) * lnt_over);
    float c0 = cosf((float)s * inv0), sn0 = sinf((float)s * inv0);
    float c1 = cosf((float)s * inv1), sn1 = sinf((float)s * inv1);
    for (int h = wave; h < nh; h += 4) {
        float2 x = *(const float2*)(src + (long)m * stride + coff + h * HD + d0);
        float ss = x.x * x.x + x.y * x.y;
#pragma unroll
        for (int off = 1; off < 64; off <<= 1) ss += __shfl_xor(ss, off);
        float rs = rsqrtf(ss * (1.f / HD) + 1e-5f);
        float xn0 = x.x * rs * w0;
        float xn1 = x.y * rs * w1;
        float p0 = __shfl_xor(xn0, 32);
        float p1 = __shfl_xor(xn1, 32);
        float r0 = (lane < 32) ? -p0 : p0;   // rotate_half
        float r1 = (lane < 32) ? -p1 : p1;
        float y0 = xn0 * c0 + r0 * sn0;
        float y1 = xn1 * c1 + r1 * sn1;
        unsigned outw = (unsigned)f2bf(y0) | ((unsigned)f2bf(y1) << 16);
        *(unsigned*)(dst + (((long)(b * nh + h) * S_LEN + s) * HD + d0)) = outw;
    }
}

// ---------------- V: fp32 gout [m][coff+kh*128+d] -> bf16 TRANSPOSED [b][kh][d][s] ----------------
__global__ __launch_bounds__(256) void pack_vt(const float* __restrict__ src, u16* __restrict__ dst,
                                               int stride, int coff) {
    __shared__ u16 t[128 * 72];  // [d][s], rows padded 64->72
    const int tid = threadIdx.x;
    const int st = blockIdx.x & 31;
    const int kh = (blockIdx.x >> 5) & 3;
    const int b = blockIdx.x >> 7;
    const long m0 = (long)b * S_LEN + st * 64;
#pragma unroll
    for (int c = 0; c < 8; c++) {
        int idx = c * 256 + tid;           // 0..2047 float4s
        int r = idx >> 5, cg = idx & 31;   // s-row 0..63, col-group 0..31
        float4 v = *(const float4*)(src + (m0 + r) * stride + coff + kh * HD + cg * 4);
        int col = cg * 4;
        t[(col + 0) * 72 + r] = f2bf(v.x);
        t[(col + 1) * 72 + r] = f2bf(v.y);
        t[(col + 2) * 72 + r] = f2bf(v.z);
        t[(col + 3) * 72 + r] = f2bf(v.w);
    }
    __syncthreads();
    const int d = tid >> 1, sh = (tid & 1) * 32;
    u16* dp = dst + ((long)(b * NKV + kh) * HD + d) * S_LEN + st * 64 + sh;
    const u16* tp = &t[d * 72 + sh];
    *(uint4*)(dp + 0)  = *(const uint4*)(tp + 0);
    *(uint4*)(dp + 8)  = *(const uint4*)(tp + 8);
    *(uint4*)(dp + 16) = *(const uint4*)(tp + 16);
    *(uint4*)(dp + 24) = *(const uint4*)(tp + 24);
}

// ---------------- MFMA flash attention v11: v7 split-K + LDS aliasing ----------------
// Exact v7 structure (split-K flash-decoding, 2048 blocks, heavy-first,
// (b,kh)->XCD map, no pairing/setprio/defer-max; measured 156.6us) with ONE
// change: Pls (18.4KB, live only in kt loop) and macc (16KB, live only in the
// post-loop merge) are ALIASED in one buffer -> LDS 37888 -> 19456 B.
// Rationale: occupancy pinned at ~2 blocks/CU across v7/v8/v10 despite
// VGPR=124 (4 waves/SIMD worth) and uniform work (v10) -> residency cap is
// LDS-side. Halving LDS tests (and if right, removes) that cap.
// Safety: mlb ([18432,19456), NOT aliased) is written pre-barrier; macc
// overlay writes happen only after the merge-entry __syncthreads(), at which
// point every wave has exited its kt loop -> no live Pls data.
__global__ __launch_bounds__(256, 2) void flash_attn(const u16* __restrict__ Q, const u16* __restrict__ K,
                                                     const u16* __restrict__ Vt, u16* __restrict__ O) {
    __shared__ __align__(16) char shmem[19456];
    u16* Pls = (u16*)shmem;                 // [0, 18432) : 4 waves x 32 rows x 72 u16
    float* maccf = (float*)shmem;           // [0, 16384) : [mt][dt][col][row] (post-barrier overlay)
    float* mlbf = (float*)(shmem + 18432);  // [18432, 19456) : [wave][mt][row][{m,l}]
#define MACC(mt, dt, c, r) (((((mt) * 8 + (dt)) * 16 + (c)) * 16) + (r))
#define MLB(w, mt, row, j) (((((w) * 2 + (mt)) * 16 + (row)) * 2) + (j))
    const int tid = threadIdx.x;
    const int wave = tid >> 6, lane = tid & 63;
    const int quad = lane >> 4, lr = lane & 15;
    const int g = blockIdx.x & 7;           // (b,kh) group -> XCD locality
    const int sub = (blockIdx.x >> 3) & 3;  // h within kv group
    const int tt = blockIdx.x >> 5;         // 0..63
    const int t = 63 - tt;                  // heavy tiles dispatched first
    const int b = g >> 2, kh = g & 3;
    const int h = kh * 4 + sub;
    const float scale = 0.08838834764831845f;  // 1/sqrt(128)
    const u16* Qb = Q + ((long)(b * NH + h) * S_LEN) * HD;
    const u16* Kb = K + ((long)(b * NKV + kh) * S_LEN) * HD;
    const u16* Vb = Vt + ((long)(b * NKV + kh) * HD) * S_LEN;
    const int pbase = wave * 32 * PST;

    const int q0 = t * 32;
    const int nkt = (t >> 1) + 1;           // key tiles of 64 covering [0, 32t+32)

    frag_ab qf[2][4];
#pragma unroll
    for (int mt = 0; mt < 2; mt++) {
        int qrow = q0 + mt * 16 + lr;
#pragma unroll
        for (int ks = 0; ks < 4; ks++)
            qf[mt][ks] = *(const frag_ab*)(Qb + (long)qrow * HD + ks * 32 + quad * 8);
    }
    frag_cd oa[2][8];
    float m_i[2][4], l_i[2][4];
#pragma unroll
    for (int mt = 0; mt < 2; mt++) {
#pragma unroll
        for (int dt = 0; dt < 8; dt++) oa[mt][dt] = (frag_cd){0.f, 0.f, 0.f, 0.f};
#pragma unroll
        for (int r = 0; r < 4; r++) { m_i[mt][r] = -3e38f; l_i[mt][r] = 0.f; }
    }

    for (int kt = wave; kt < nkt; kt += 4) {
        const int j0 = kt * 64;
        // S = Q K^T  (kf direct from global K[key][d])
        frag_cd sa[2][4];
#pragma unroll
        for (int mt = 0; mt < 2; mt++)
#pragma unroll
            for (int nt = 0; nt < 4; nt++) sa[mt][nt] = (frag_cd){0.f, 0.f, 0.f, 0.f};
#pragma unroll
        for (int nt = 0; nt < 4; nt++) {
            frag_ab kf[4];
#pragma unroll
            for (int ks = 0; ks < 4; ks++)
                kf[ks] = *(const frag_ab*)(Kb + (long)(j0 + nt * 16 + lr) * HD + ks * 32 + quad * 8);
#pragma unroll
            for (int mt = 0; mt < 2; mt++)
#pragma unroll
                for (int ks = 0; ks < 4; ks++)
                    sa[mt][nt] = __builtin_amdgcn_mfma_f32_16x16x32_bf16(qf[mt][ks], kf[ks], sa[mt][nt], 0, 0, 0);
        }
        // early V fragment loads (hide latency under softmax)
        frag_ab vf[2][8];
#pragma unroll
        for (int ks = 0; ks < 2; ks++)
#pragma unroll
            for (int dt = 0; dt < 8; dt++)
                vf[ks][dt] = *(const frag_ab*)(Vb + (long)(dt * 16 + lr) * S_LEN + j0 + ks * 32 + quad * 8);

        const bool need_mask = (j0 + 63) > q0;
        // online softmax (C-layout: row=quad*4+r, col=lr)
#pragma unroll
        for (int mt = 0; mt < 2; mt++) {
            float mrow[4] = {-3e38f, -3e38f, -3e38f, -3e38f};
#pragma unroll
            for (int nt = 0; nt < 4; nt++) {
                int key = j0 + nt * 16 + lr;
#pragma unroll
                for (int r = 0; r < 4; r++) {
                    int qrow = q0 + mt * 16 + quad * 4 + r;
                    float v = sa[mt][nt][r] * scale;
                    if (need_mask) v = (key <= qrow) ? v : -3e38f;
                    sa[mt][nt][r] = v;
                    mrow[r] = fmaxf(mrow[r], v);
                }
            }
#pragma unroll
            for (int off = 1; off < 16; off <<= 1)
#pragma unroll
                for (int r = 0; r < 4; r++) mrow[r] = fmaxf(mrow[r], __shfl_xor(mrow[r], off));
            float rs[4];
#pragma unroll
            for (int r = 0; r < 4; r++) {
                float mn = fmaxf(m_i[mt][r], mrow[r]);
                float alpha = __expf(m_i[mt][r] - mn);
                m_i[mt][r] = mn;
                l_i[mt][r] *= alpha;
                rs[r] = 0.f;
#pragma unroll
                for (int dt = 0; dt < 8; dt++) oa[mt][dt][r] *= alpha;
            }
#pragma unroll
            for (int nt = 0; nt < 4; nt++)
#pragma unroll
                for (int r = 0; r < 4; r++) {
                    float pw = __expf(sa[mt][nt][r] - m_i[mt][r]);
                    rs[r] += pw;
                    Pls[pbase + (mt * 16 + quad * 4 + r) * PST + nt * 16 + lr] = f2bf(pw);
                }
#pragma unroll
            for (int off = 1; off < 16; off <<= 1)
#pragma unroll
                for (int r = 0; r < 4; r++) rs[r] += __shfl_xor(rs[r], off);
#pragma unroll
            for (int r = 0; r < 4; r++) l_i[mt][r] += rs[r];
        }

        // O += P V  (pf via per-wave LDS; vf pre-loaded)
#pragma unroll
        for (int ks = 0; ks < 2; ks++) {
            frag_ab pf[2];
#pragma unroll
            for (int mt = 0; mt < 2; mt++)
                pf[mt] = *(const frag_ab*)&Pls[pbase + (mt * 16 + lr) * PST + ks * 32 + quad * 8];
#pragma unroll
            for (int dt = 0; dt < 8; dt++) {
                oa[0][dt] = __builtin_amdgcn_mfma_f32_16x16x32_bf16(pf[0], vf[ks][dt], oa[0][dt], 0, 0, 0);
                oa[1][dt] = __builtin_amdgcn_mfma_f32_16x16x32_bf16(pf[1], vf[ks][dt], oa[1][dt], 0, 0, 0);
            }
        }
    }

    // ---- flash-decoding merge across the 4 waves ----
    // publish per-wave (m, l) into mlb (NOT aliased with Pls; safe pre-barrier)
    if (lr == 0) {
#pragma unroll
        for (int mt = 0; mt < 2; mt++)
#pragma unroll
            for (int r = 0; r < 4; r++) {
                mlbf[MLB(wave, mt, quad * 4 + r, 0)] = m_i[mt][r];
                mlbf[MLB(wave, mt, quad * 4 + r, 1)] = l_i[mt][r];
            }
    }
    __syncthreads();   // ALL waves past kt loop -> Pls dead; macc overlay now safe
    // global max + merged denom; rescale own accumulator in-reg
    float inv[2][4];
#pragma unroll
    for (int mt = 0; mt < 2; mt++)
#pragma unroll
        for (int r = 0; r < 4; r++) {
            int row = quad * 4 + r;
            float m0 = mlbf[MLB(0, mt, row, 0)], m1 = mlbf[MLB(1, mt, row, 0)];
            float m2 = mlbf[MLB(2, mt, row, 0)], m3 = mlbf[MLB(3, mt, row, 0)];
            float ms = fmaxf(fmaxf(m0, m1), fmaxf(m2, m3));
            float ls = mlbf[MLB(0, mt, row, 1)] * __expf(m0 - ms) + mlbf[MLB(1, mt, row, 1)] * __expf(m1 - ms)
                     + mlbf[MLB(2, mt, row, 1)] * __expf(m2 - ms) + mlbf[MLB(3, mt, row, 1)] * __expf(m3 - ms);
            inv[mt][r] = 1.f / ls;
            float alpha = __expf(m_i[mt][r] - ms);   // 0 for waves with no work
#pragma unroll
            for (int dt = 0; dt < 8; dt++) oa[mt][dt][r] *= alpha;
        }
    // serialized accumulate into macc overlay (float4 rows: [mt][dt][col=lr][row quad*4..+3])
    for (int w = 0; w < 4; w++) {
        if (wave == w) {
#pragma unroll
            for (int mt = 0; mt < 2; mt++)
#pragma unroll
                for (int dt = 0; dt < 8; dt++) {
                    frag_cd* pp = (frag_cd*)&maccf[MACC(mt, dt, lr, quad * 4)];
                    if (w == 0) *pp = oa[mt][dt];
                    else {
                        frag_cd o = *pp;
#pragma unroll
                        for (int r = 0; r < 4; r++) o[r] += oa[mt][dt][r];
                        *pp = o;
                    }
                }
        }
        __syncthreads();
    }
    // cooperative epilogue: wave handles dt = 2*wave, 2*wave+1
#pragma unroll
    for (int mt = 0; mt < 2; mt++)
#pragma unroll
        for (int dto = 0; dto < 2; dto++) {
            int dt = wave * 2 + dto;
            frag_cd v = *(const frag_cd*)&maccf[MACC(mt, dt, lr, quad * 4)];
#pragma unroll
            for (int r = 0; r < 4; r++) {
                int s = q0 + mt * 16 + quad * 4 + r;
                O[((long)b * S_LEN + s) * (NH * HD) + h * HD + dt * 16 + lr] =
                    f2bf(v[r] * inv[mt][r]);
            }
        }
#undef MACC
#undef MLB
}

extern "C" void kernel_launch(void* const* d_in, const int* in_sizes, int n_in,
                              void* d_out, int out_size, void* d_ws, size_t ws_size,
                              hipStream_t stream) {
    const float* hs  = (const float*)d_in[0];
    const float* q_w = (const float*)d_in[1];
    const float* k_w = (const float*)d_in[2];
    const float* v_w = (const float*)d_in[3];
    const float* o_w = (const float*)d_in[4];
    const float* qnw = (const float*)d_in[5];
    const float* knw = (const float*)d_in[6];
    float* out = (float*)d_out;

    // Workspace (72 MiB, live ranges stream-serialized & disjoint):
    //   [ 0,16M) hs_bf : hidden bf16; later attn-out bf16
    //   [16,24M) wbuf  : weights bf16 (Q 8M; then KV 4M; then O 8M)
    //   [24,56M) gout  : fp32 GEMM out (Q all 32M; KV uses [24,40) only)
    //   [40,44M) Kr    : bf16 [b][4][s][128]
    //   [44,48M) Vt    : bf16 [b][4][d][s] transposed
    //   [56,72M) Qr    : bf16 [b][16][s][128]
    char* ws = (char*)d_ws;
    u16* hs_bf  = (u16*)(ws);
    u16* wbuf   = (u16*)(ws + (16ul << 20));
    float* gout = (float*)(ws + (24ul << 20));
    u16* Kr     = (u16*)(ws + (40ul << 20));
    u16* Vt     = (u16*)(ws + (44ul << 20));
    u16* Qr     = (u16*)(ws + (56ul << 20));
    (void)ws_size; (void)in_sizes; (void)n_in; (void)out_size;

    // hidden -> bf16
    conv_f32_bf16<<<(MROWS * HID / 4 + 255) / 256, 256, 0, stream>>>(hs, hs_bf, MROWS * HID / 4);

    // Q = hs @ q_w^T ; rmsnorm + rope
    conv_f32_bf16<<<(HID * HID / 4 + 255) / 256, 256, 0, stream>>>(q_w, wbuf, HID * HID / 4);
    dim3 gq(MROWS / 128, HID / 128);
    gemm_bt<<<gq, 256, 0, stream>>>(hs_bf, wbuf, gout, MROWS, HID, HID);
    rope_norm<<<MROWS, 256, 0, stream>>>(gout, Qr, qnw, NH, HID, 0);

    // K|V fused projection: wbuf rows [0,512)=k_w, [512,1024)=v_w; N=1024
    conv_f32_bf16<<<(NKV * HD * HID / 4 + 255) / 256, 256, 0, stream>>>(k_w, wbuf, NKV * HD * HID / 4);
    conv_f32_bf16<<<(NKV * HD * HID / 4 + 255) / 256, 256, 0, stream>>>(v_w, wbuf + NKV * HD * HID, NKV * HD * HID / 4);
    dim3 gkv(MROWS / 128, (2 * NKV * HD) / 128);
    gemm_bt<<<gkv, 256, 0, stream>>>(hs_bf, wbuf, gout, MROWS, 2 * NKV * HD, HID);
    rope_norm<<<MROWS, 256, 0, stream>>>(gout, Kr, knw, NKV, 2 * NKV * HD, 0);
    pack_vt<<<BATCH * NKV * (S_LEN / 64), 256, 0, stream>>>(gout, Vt, 2 * NKV * HD, NKV * HD);

    // attention -> hs_bf  (grid = 64 tiles x 32 bh = 2048, 4-wave split-K blocks)
    flash_attn<<<2048, 256, 0, stream>>>(Qr, Kr, Vt, hs_bf);

    // out = attn @ o_w^T
    conv_f32_bf16<<<(HID * HID / 4 + 255) / 256, 256, 0, stream>>>(o_w, wbuf, HID * HID / 4);
    gemm_bt<<<gq, 256, 0, stream>>>(hs_bf, wbuf, out, MROWS, HID, HID);
}

// Round 10
// 423.219 us; speedup vs baseline: 1.8164x; 1.0596x over previous
//
#include <hip/hip_runtime.h>
#include <stdint.h>

#define S_LEN 2048
#define BATCH 2
#define NH 16
#define NKV 4
#define HD 128
#define HID 2048
#define MROWS (BATCH * S_LEN)  // 4096
#define PST 72                 // Pls row stride (u16): 144B = 9x16B -> 2-way bank alias (free)

typedef unsigned short u16;
typedef __attribute__((ext_vector_type(8))) short frag_ab;
typedef __attribute__((ext_vector_type(4))) float frag_cd;

static __device__ __forceinline__ float bf2f(u16 v) {
    union { unsigned u; float f; } t; t.u = ((unsigned)v) << 16; return t.f;
}
static __device__ __forceinline__ u16 f2bf(float f) {
    union { float f; unsigned u; } t; t.f = f;
    unsigned r = t.u + 0x7fffu + ((t.u >> 16) & 1u);  // RNE
    return (u16)(r >> 16);
}
// async global->LDS, 16B per lane; LDS dest = wave-uniform base + lane*16
static __device__ __forceinline__ void load_lds16(const u16* g, u16* l) {
    __builtin_amdgcn_global_load_lds((const __attribute__((address_space(1))) void*)g,
                                     (__attribute__((address_space(3))) void*)l, 16, 0, 0);
}

// ---------------- fp32 -> bf16 bulk convert ----------------
__global__ __launch_bounds__(256) void conv_f32_bf16(const float* __restrict__ src,
                                                     u16* __restrict__ dst, int n4) {
    int i = blockIdx.x * 256 + threadIdx.x;
    if (i >= n4) return;
    float4 v = ((const float4*)src)[i];
    ushort4 o;
    o.x = f2bf(v.x); o.y = f2bf(v.y); o.z = f2bf(v.z); o.w = f2bf(v.w);
    ((ushort4*)dst)[i] = o;
}

// ---------------- C = A (MxK) * B^T (B stored [N][K]), fp32 out ----------------
// 128x128 tile, 4 waves x (4x4) 16x16x32 MFMA, BK=32, global_load_lds width=16
// staging (m97 ladder step 3).
__global__ __launch_bounds__(256) void gemm_bt(const u16* __restrict__ A, const u16* __restrict__ B,
                                               float* __restrict__ C, int M, int N, int K) {
    __shared__ u16 As[128 * 32];
    __shared__ u16 Bs[128 * 32];
    const int tid = threadIdx.x;
    const int wave = tid >> 6, lane = tid & 63;
    const int quad = lane >> 4, lr = lane & 15;
    const int wm = (wave & 1) * 64, wn = (wave >> 1) * 64;
    const long bm = (long)blockIdx.x * 128, bn = (long)blockIdx.y * 128;
    // staging: chunk c = issue*256 + wave*64 + lane; row=c>>2, col16=c&3
    const int srow = (wave << 4) + (lane >> 2);   // + issue*64
    const int scol = (lane & 3) * 8;
    const u16* Ag = A + (bm + srow) * (long)K + scol;
    const u16* Bg = B + (bn + srow) * (long)K + scol;
    u16* AsW = As + wave * 512;                    // + issue*2048 (u16)
    u16* BsW = Bs + wave * 512;

    frag_cd acc[4][4];
#pragma unroll
    for (int i = 0; i < 4; i++)
#pragma unroll
        for (int j = 0; j < 4; j++) acc[i][j] = (frag_cd){0.f, 0.f, 0.f, 0.f};

    for (int k0 = 0; k0 < K; k0 += 32) {
        __syncthreads();  // prev iter's LDS readers done
        load_lds16(Ag + k0, AsW);
        load_lds16(Ag + (long)64 * K + k0, AsW + 2048);
        load_lds16(Bg + k0, BsW);
        load_lds16(Bg + (long)64 * K + k0, BsW + 2048);
        __syncthreads();  // staging complete (vmcnt(0) drained by barrier)
        frag_ab af[4], bfr[4];
#pragma unroll
        for (int i = 0; i < 4; i++) af[i] = *(const frag_ab*)(As + (wm + i * 16 + lr) * 32 + quad * 8);
#pragma unroll
        for (int j = 0; j < 4; j++) bfr[j] = *(const frag_ab*)(Bs + (wn + j * 16 + lr) * 32 + quad * 8);
#pragma unroll
        for (int i = 0; i < 4; i++)
#pragma unroll
            for (int j = 0; j < 4; j++)
                acc[i][j] = __builtin_amdgcn_mfma_f32_16x16x32_bf16(af[i], bfr[j], acc[i][j], 0, 0, 0);
    }
    // C/D layout: col = lane&15, row = (lane>>4)*4 + reg   [measured m89/m91]
#pragma unroll
    for (int i = 0; i < 4; i++)
#pragma unroll
        for (int j = 0; j < 4; j++)
#pragma unroll
            for (int r = 0; r < 4; r++) {
                long row = bm + wm + i * 16 + quad * 4 + r;
                long col = bn + wn + j * 16 + lr;
                C[row * N + col] = acc[i][j][r];
            }
}

// ---------------- BN=64 variant: C = A (Mx K) * B^T, 128x64 tile ----------------
// 4 waves as 2M x 2N: wm=(wave&1)*64, wn=(wave>>1)*32; acc[4][2]; 3 staging
// loads/iter (A 128x32, B 64x32); LDS 12KB. Purpose: 2x the block count for
// skinny-N gemms (O-proj N=2048 -> 1024 blocks = 4/CU; KV N=1024 -> 2/CU)
// whose 128x128 grids were latency-starved at 1-2 blocks/CU.
__global__ __launch_bounds__(256) void gemm_bt64(const u16* __restrict__ A, const u16* __restrict__ B,
                                                 float* __restrict__ C, int M, int N, int K) {
    __shared__ u16 As[128 * 32];
    __shared__ u16 Bs[64 * 32];
    const int tid = threadIdx.x;
    const int wave = tid >> 6, lane = tid & 63;
    const int quad = lane >> 4, lr = lane & 15;
    const int wm = (wave & 1) * 64, wn = (wave >> 1) * 32;
    const long bm = (long)blockIdx.x * 128, bn = (long)blockIdx.y * 64;
    const int srow = (wave << 4) + (lane >> 2);   // rows [0,64) across 4 waves
    const int scol = (lane & 3) * 8;
    const u16* Ag = A + (bm + srow) * (long)K + scol;
    const u16* Bg = B + (bn + srow) * (long)K + scol;
    u16* AsW = As + wave * 512;
    u16* BsW = Bs + wave * 512;

    frag_cd acc[4][2];
#pragma unroll
    for (int i = 0; i < 4; i++)
#pragma unroll
        for (int j = 0; j < 2; j++) acc[i][j] = (frag_cd){0.f, 0.f, 0.f, 0.f};

    for (int k0 = 0; k0 < K; k0 += 32) {
        __syncthreads();
        load_lds16(Ag + k0, AsW);
        load_lds16(Ag + (long)64 * K + k0, AsW + 2048);
        load_lds16(Bg + k0, BsW);
        __syncthreads();
        frag_ab af[4], bfr[2];
#pragma unroll
        for (int i = 0; i < 4; i++) af[i] = *(const frag_ab*)(As + (wm + i * 16 + lr) * 32 + quad * 8);
#pragma unroll
        for (int j = 0; j < 2; j++) bfr[j] = *(const frag_ab*)(Bs + (wn + j * 16 + lr) * 32 + quad * 8);
#pragma unroll
        for (int i = 0; i < 4; i++)
#pragma unroll
            for (int j = 0; j < 2; j++)
                acc[i][j] = __builtin_amdgcn_mfma_f32_16x16x32_bf16(af[i], bfr[j], acc[i][j], 0, 0, 0);
    }
#pragma unroll
    for (int i = 0; i < 4; i++)
#pragma unroll
        for (int j = 0; j < 2; j++)
#pragma unroll
            for (int r = 0; r < 4; r++) {
                long row = bm + wm + i * 16 + quad * 4 + r;
                long col = bn + wn + j * 16 + lr;
                C[row * N + col] = acc[i][j][r];
            }
}

// ---------------- RMSNorm(head_dim) + RoPE, fp32 in -> bf16 out [b][h][s][d] ----------------
__global__ __launch_bounds__(256) void rope_norm(const float* __restrict__ src, u16* __restrict__ dst,
                                                 const float* __restrict__ nw, int nh, int stride, int coff) {
    const int m = blockIdx.x;                 // 0..4095 (b*S+s)
    const int wave = threadIdx.x >> 6, lane = threadIdx.x & 63;
    const int s = m & (S_LEN - 1), b = m >> 11;
    const int d0 = 2 * lane;
    const float w0 = nw[d0], w1 = nw[d0 + 1];
    const int i0 = d0 & 63;
    const float lnt_over = 13.122363377404328f / 64.f;  // ln(500000)/64
    float inv0 = expf(-(float)i0 * lnt_over);
    float inv1 = expf(-(float)(i0 + 1) * lnt_over);
    float c0 = cosf((float)s * inv0), sn0 = sinf((float)s * inv0);
    float c1 = cosf((float)s * inv1), sn1 = sinf((float)s * inv1);
    for (int h = wave; h < nh; h += 4) {
        float2 x = *(const float2*)(src + (long)m * stride + coff + h * HD + d0);
        float ss = x.x * x.x + x.y * x.y;
#pragma unroll
        for (int off = 1; off < 64; off <<= 1) ss += __shfl_xor(ss, off);
        float rs = rsqrtf(ss * (1.f / HD) + 1e-5f);
        float xn0 = x.x * rs * w0;
        float xn1 = x.y * rs * w1;
        float p0 = __shfl_xor(xn0, 32);
        float p1 = __shfl_xor(xn1, 32);
        float r0 = (lane < 32) ? -p0 : p0;   // rotate_half
        float r1 = (lane < 32) ? -p1 : p1;
        float y0 = xn0 * c0 + r0 * sn0;
        float y1 = xn1 * c1 + r1 * sn1;
        unsigned outw = (unsigned)f2bf(y0) | ((unsigned)f2bf(y1) << 16);
        *(unsigned*)(dst + (((long)(b * nh + h) * S_LEN + s) * HD + d0)) = outw;
    }
}

// ---------------- V: fp32 gout [m][coff+kh*128+d] -> bf16 TRANSPOSED [b][kh][d][s] ----------------
__global__ __launch_bounds__(256) void pack_vt(const float* __restrict__ src, u16* __restrict__ dst,
                                               int stride, int coff) {
    __shared__ u16 t[128 * 72];  // [d][s], rows padded 64->72
    const int tid = threadIdx.x;
    const int st = blockIdx.x & 31;
    const int kh = (blockIdx.x >> 5) & 3;
    const int b = blockIdx.x >> 7;
    const long m0 = (long)b * S_LEN + st * 64;
#pragma unroll
    for (int c = 0; c < 8; c++) {
        int idx = c * 256 + tid;           // 0..2047 float4s
        int r = idx >> 5, cg = idx & 31;   // s-row 0..63, col-group 0..31
        float4 v = *(const float4*)(src + (m0 + r) * stride + coff + kh * HD + cg * 4);
        int col = cg * 4;
        t[(col + 0) * 72 + r] = f2bf(v.x);
        t[(col + 1) * 72 + r] = f2bf(v.y);
        t[(col + 2) * 72 + r] = f2bf(v.z);
        t[(col + 3) * 72 + r] = f2bf(v.w);
    }
    __syncthreads();
    const int d = tid >> 1, sh = (tid & 1) * 32;
    u16* dp = dst + ((long)(b * NKV + kh) * HD + d) * S_LEN + st * 64 + sh;
    const u16* tp = &t[d * 72 + sh];
    *(uint4*)(dp + 0)  = *(const uint4*)(tp + 0);
    *(uint4*)(dp + 8)  = *(const uint4*)(tp + 8);
    *(uint4*)(dp + 16) = *(const uint4*)(tp + 16);
    *(uint4*)(dp + 24) = *(const uint4*)(tp + 24);
}

// ---------------- MFMA flash attention v11: v7 split-K + LDS aliasing (measured 156.3us) ----------------
__global__ __launch_bounds__(256, 2) void flash_attn(const u16* __restrict__ Q, const u16* __restrict__ K,
                                                     const u16* __restrict__ Vt, u16* __restrict__ O) {
    __shared__ __align__(16) char shmem[19456];
    u16* Pls = (u16*)shmem;                 // [0, 18432) : 4 waves x 32 rows x 72 u16
    float* maccf = (float*)shmem;           // [0, 16384) : [mt][dt][col][row] (post-barrier overlay)
    float* mlbf = (float*)(shmem + 18432);  // [18432, 19456) : [wave][mt][row][{m,l}]
#define MACC(mt, dt, c, r) (((((mt) * 8 + (dt)) * 16 + (c)) * 16) + (r))
#define MLB(w, mt, row, j) (((((w) * 2 + (mt)) * 16 + (row)) * 2) + (j))
    const int tid = threadIdx.x;
    const int wave = tid >> 6, lane = tid & 63;
    const int quad = lane >> 4, lr = lane & 15;
    const int g = blockIdx.x & 7;           // (b,kh) group -> XCD locality
    const int sub = (blockIdx.x >> 3) & 3;  // h within kv group
    const int tt = blockIdx.x >> 5;         // 0..63
    const int t = 63 - tt;                  // heavy tiles dispatched first
    const int b = g >> 2, kh = g & 3;
    const int h = kh * 4 + sub;
    const float scale = 0.08838834764831845f;  // 1/sqrt(128)
    const u16* Qb = Q + ((long)(b * NH + h) * S_LEN) * HD;
    const u16* Kb = K + ((long)(b * NKV + kh) * S_LEN) * HD;
    const u16* Vb = Vt + ((long)(b * NKV + kh) * HD) * S_LEN;
    const int pbase = wave * 32 * PST;

    const int q0 = t * 32;
    const int nkt = (t >> 1) + 1;           // key tiles of 64 covering [0, 32t+32)

    frag_ab qf[2][4];
#pragma unroll
    for (int mt = 0; mt < 2; mt++) {
        int qrow = q0 + mt * 16 + lr;
#pragma unroll
        for (int ks = 0; ks < 4; ks++)
            qf[mt][ks] = *(const frag_ab*)(Qb + (long)qrow * HD + ks * 32 + quad * 8);
    }
    frag_cd oa[2][8];
    float m_i[2][4], l_i[2][4];
#pragma unroll
    for (int mt = 0; mt < 2; mt++) {
#pragma unroll
        for (int dt = 0; dt < 8; dt++) oa[mt][dt] = (frag_cd){0.f, 0.f, 0.f, 0.f};
#pragma unroll
        for (int r = 0; r < 4; r++) { m_i[mt][r] = -3e38f; l_i[mt][r] = 0.f; }
    }

    for (int kt = wave; kt < nkt; kt += 4) {
        const int j0 = kt * 64;
        // S = Q K^T  (kf direct from global K[key][d])
        frag_cd sa[2][4];
#pragma unroll
        for (int mt = 0; mt < 2; mt++)
#pragma unroll
            for (int nt = 0; nt < 4; nt++) sa[mt][nt] = (frag_cd){0.f, 0.f, 0.f, 0.f};
#pragma unroll
        for (int nt = 0; nt < 4; nt++) {
            frag_ab kf[4];
#pragma unroll
            for (int ks = 0; ks < 4; ks++)
                kf[ks] = *(const frag_ab*)(Kb + (long)(j0 + nt * 16 + lr) * HD + ks * 32 + quad * 8);
#pragma unroll
            for (int mt = 0; mt < 2; mt++)
#pragma unroll
                for (int ks = 0; ks < 4; ks++)
                    sa[mt][nt] = __builtin_amdgcn_mfma_f32_16x16x32_bf16(qf[mt][ks], kf[ks], sa[mt][nt], 0, 0, 0);
        }
        // early V fragment loads (hide latency under softmax)
        frag_ab vf[2][8];
#pragma unroll
        for (int ks = 0; ks < 2; ks++)
#pragma unroll
            for (int dt = 0; dt < 8; dt++)
                vf[ks][dt] = *(const frag_ab*)(Vb + (long)(dt * 16 + lr) * S_LEN + j0 + ks * 32 + quad * 8);

        const bool need_mask = (j0 + 63) > q0;
        // online softmax (C-layout: row=quad*4+r, col=lr)
#pragma unroll
        for (int mt = 0; mt < 2; mt++) {
            float mrow[4] = {-3e38f, -3e38f, -3e38f, -3e38f};
#pragma unroll
            for (int nt = 0; nt < 4; nt++) {
                int key = j0 + nt * 16 + lr;
#pragma unroll
                for (int r = 0; r < 4; r++) {
                    int qrow = q0 + mt * 16 + quad * 4 + r;
                    float v = sa[mt][nt][r] * scale;
                    if (need_mask) v = (key <= qrow) ? v : -3e38f;
                    sa[mt][nt][r] = v;
                    mrow[r] = fmaxf(mrow[r], v);
                }
            }
#pragma unroll
            for (int off = 1; off < 16; off <<= 1)
#pragma unroll
                for (int r = 0; r < 4; r++) mrow[r] = fmaxf(mrow[r], __shfl_xor(mrow[r], off));
            float rs[4];
#pragma unroll
            for (int r = 0; r < 4; r++) {
                float mn = fmaxf(m_i[mt][r], mrow[r]);
                float alpha = __expf(m_i[mt][r] - mn);
                m_i[mt][r] = mn;
                l_i[mt][r] *= alpha;
                rs[r] = 0.f;
#pragma unroll
                for (int dt = 0; dt < 8; dt++) oa[mt][dt][r] *= alpha;
            }
#pragma unroll
            for (int nt = 0; nt < 4; nt++)
#pragma unroll
                for (int r = 0; r < 4; r++) {
                    float pw = __expf(sa[mt][nt][r] - m_i[mt][r]);
                    rs[r] += pw;
                    Pls[pbase + (mt * 16 + quad * 4 + r) * PST + nt * 16 + lr] = f2bf(pw);
                }
#pragma unroll
            for (int off = 1; off < 16; off <<= 1)
#pragma unroll
                for (int r = 0; r < 4; r++) rs[r] += __shfl_xor(rs[r], off);
#pragma unroll
            for (int r = 0; r < 4; r++) l_i[mt][r] += rs[r];
        }

        // O += P V  (pf via per-wave LDS; vf pre-loaded)
#pragma unroll
        for (int ks = 0; ks < 2; ks++) {
            frag_ab pf[2];
#pragma unroll
            for (int mt = 0; mt < 2; mt++)
                pf[mt] = *(const frag_ab*)&Pls[pbase + (mt * 16 + lr) * PST + ks * 32 + quad * 8];
#pragma unroll
            for (int dt = 0; dt < 8; dt++) {
                oa[0][dt] = __builtin_amdgcn_mfma_f32_16x16x32_bf16(pf[0], vf[ks][dt], oa[0][dt], 0, 0, 0);
                oa[1][dt] = __builtin_amdgcn_mfma_f32_16x16x32_bf16(pf[1], vf[ks][dt], oa[1][dt], 0, 0, 0);
            }
        }
    }

    // ---- flash-decoding merge across the 4 waves ----
    // publish per-wave (m, l) into mlb (NOT aliased with Pls; safe pre-barrier)
    if (lr == 0) {
#pragma unroll
        for (int mt = 0; mt < 2; mt++)
#pragma unroll
            for (int r = 0; r < 4; r++) {
                mlbf[MLB(wave, mt, quad * 4 + r, 0)] = m_i[mt][r];
                mlbf[MLB(wave, mt, quad * 4 + r, 1)] = l_i[mt][r];
            }
    }
    __syncthreads();   // ALL waves past kt loop -> Pls dead; macc overlay now safe
    // global max + merged denom; rescale own accumulator in-reg
    float inv[2][4];
#pragma unroll
    for (int mt = 0; mt < 2; mt++)
#pragma unroll
        for (int r = 0; r < 4; r++) {
            int row = quad * 4 + r;
            float m0 = mlbf[MLB(0, mt, row, 0)], m1 = mlbf[MLB(1, mt, row, 0)];
            float m2 = mlbf[MLB(2, mt, row, 0)], m3 = mlbf[MLB(3, mt, row, 0)];
            float ms = fmaxf(fmaxf(m0, m1), fmaxf(m2, m3));
            float ls = mlbf[MLB(0, mt, row, 1)] * __expf(m0 - ms) + mlbf[MLB(1, mt, row, 1)] * __expf(m1 - ms)
                     + mlbf[MLB(2, mt, row, 1)] * __expf(m2 - ms) + mlbf[MLB(3, mt, row, 1)] * __expf(m3 - ms);
            inv[mt][r] = 1.f / ls;
            float alpha = __expf(m_i[mt][r] - ms);   // 0 for waves with no work
#pragma unroll
            for (int dt = 0; dt < 8; dt++) oa[mt][dt][r] *= alpha;
        }
    // serialized accumulate into macc overlay (float4 rows: [mt][dt][col=lr][row quad*4..+3])
    for (int w = 0; w < 4; w++) {
        if (wave == w) {
#pragma unroll
            for (int mt = 0; mt < 2; mt++)
#pragma unroll
                for (int dt = 0; dt < 8; dt++) {
                    frag_cd* pp = (frag_cd*)&maccf[MACC(mt, dt, lr, quad * 4)];
                    if (w == 0) *pp = oa[mt][dt];
                    else {
                        frag_cd o = *pp;
#pragma unroll
                        for (int r = 0; r < 4; r++) o[r] += oa[mt][dt][r];
                        *pp = o;
                    }
                }
        }
        __syncthreads();
    }
    // cooperative epilogue: wave handles dt = 2*wave, 2*wave+1
#pragma unroll
    for (int mt = 0; mt < 2; mt++)
#pragma unroll
        for (int dto = 0; dto < 2; dto++) {
            int dt = wave * 2 + dto;
            frag_cd v = *(const frag_cd*)&maccf[MACC(mt, dt, lr, quad * 4)];
#pragma unroll
            for (int r = 0; r < 4; r++) {
                int s = q0 + mt * 16 + quad * 4 + r;
                O[((long)b * S_LEN + s) * (NH * HD) + h * HD + dt * 16 + lr] =
                    f2bf(v[r] * inv[mt][r]);
            }
        }
#undef MACC
#undef MLB
}

extern "C" void kernel_launch(void* const* d_in, const int* in_sizes, int n_in,
                              void* d_out, int out_size, void* d_ws, size_t ws_size,
                              hipStream_t stream) {
    const float* hs  = (const float*)d_in[0];
    const float* q_w = (const float*)d_in[1];
    const float* k_w = (const float*)d_in[2];
    const float* v_w = (const float*)d_in[3];
    const float* o_w = (const float*)d_in[4];
    const float* qnw = (const float*)d_in[5];
    const float* knw = (const float*)d_in[6];
    float* out = (float*)d_out;
    char* ws = (char*)d_ws;
    (void)in_sizes; (void)n_in; (void)out_size;

    if (ws_size >= (100ul << 20)) {
        // ---- big-workspace path: fused QKV projection (N=3072, 3 blocks/CU) ----
        // [ 0, 16M) hs_bf : hidden bf16; later attn-out bf16
        // [16, 28M) wbuf  : weights bf16 (q|k|v rows 0..3071; later O 8M)
        // [28, 76M) gout  : fp32 QKV GEMM out [4096][3072]
        // [76, 80M) Kr ; [80, 84M) Vt ; [84,100M) Qr
        u16* hs_bf  = (u16*)(ws);
        u16* wbuf   = (u16*)(ws + (16ul << 20));
        float* gout = (float*)(ws + (28ul << 20));
        u16* Kr     = (u16*)(ws + (76ul << 20));
        u16* Vt     = (u16*)(ws + (80ul << 20));
        u16* Qr     = (u16*)(ws + (84ul << 20));
        const int NQKV = HID + 2 * NKV * HD;  // 3072

        conv_f32_bf16<<<(MROWS * HID / 4 + 255) / 256, 256, 0, stream>>>(hs, hs_bf, MROWS * HID / 4);
        conv_f32_bf16<<<(HID * HID / 4 + 255) / 256, 256, 0, stream>>>(q_w, wbuf, HID * HID / 4);
        conv_f32_bf16<<<(NKV * HD * HID / 4 + 255) / 256, 256, 0, stream>>>(k_w, wbuf + (long)HID * HID, NKV * HD * HID / 4);
        conv_f32_bf16<<<(NKV * HD * HID / 4 + 255) / 256, 256, 0, stream>>>(v_w, wbuf + (long)(HID + NKV * HD) * HID, NKV * HD * HID / 4);

        dim3 gqkv(MROWS / 128, NQKV / 128);  // (32, 24) = 768 blocks = 3/CU
        gemm_bt<<<gqkv, 256, 0, stream>>>(hs_bf, wbuf, gout, MROWS, NQKV, HID);

        rope_norm<<<MROWS, 256, 0, stream>>>(gout, Qr, qnw, NH, NQKV, 0);
        rope_norm<<<MROWS, 256, 0, stream>>>(gout, Kr, knw, NKV, NQKV, HID);
        pack_vt<<<BATCH * NKV * (S_LEN / 64), 256, 0, stream>>>(gout, Vt, NQKV, HID + NKV * HD);

        flash_attn<<<2048, 256, 0, stream>>>(Qr, Kr, Vt, hs_bf);

        conv_f32_bf16<<<(HID * HID / 4 + 255) / 256, 256, 0, stream>>>(o_w, wbuf, HID * HID / 4);
        dim3 go(MROWS / 128, HID / 64);      // (32, 32) = 1024 blocks = 4/CU
        gemm_bt64<<<go, 256, 0, stream>>>(hs_bf, wbuf, out, MROWS, HID, HID);
    } else {
        // ---- fallback 72MB path (round-9 layout); gemm_bt64 lifts KV 1->2 and O 2->4 blocks/CU ----
        u16* hs_bf  = (u16*)(ws);
        u16* wbuf   = (u16*)(ws + (16ul << 20));
        float* gout = (float*)(ws + (24ul << 20));
        u16* Kr     = (u16*)(ws + (40ul << 20));
        u16* Vt     = (u16*)(ws + (44ul << 20));
        u16* Qr     = (u16*)(ws + (56ul << 20));

        conv_f32_bf16<<<(MROWS * HID / 4 + 255) / 256, 256, 0, stream>>>(hs, hs_bf, MROWS * HID / 4);

        conv_f32_bf16<<<(HID * HID / 4 + 255) / 256, 256, 0, stream>>>(q_w, wbuf, HID * HID / 4);
        dim3 gq(MROWS / 128, HID / 128);
        gemm_bt<<<gq, 256, 0, stream>>>(hs_bf, wbuf, gout, MROWS, HID, HID);
        rope_norm<<<MROWS, 256, 0, stream>>>(gout, Qr, qnw, NH, HID, 0);

        conv_f32_bf16<<<(NKV * HD * HID / 4 + 255) / 256, 256, 0, stream>>>(k_w, wbuf, NKV * HD * HID / 4);
        conv_f32_bf16<<<(NKV * HD * HID / 4 + 255) / 256, 256, 0, stream>>>(v_w, wbuf + NKV * HD * HID, NKV * HD * HID / 4);
        dim3 gkv(MROWS / 128, (2 * NKV * HD) / 64);   // (32, 16) = 512 blocks = 2/CU
        gemm_bt64<<<gkv, 256, 0, stream>>>(hs_bf, wbuf, gout, MROWS, 2 * NKV * HD, HID);
        rope_norm<<<MROWS, 256, 0, stream>>>(gout, Kr, knw, NKV, 2 * NKV * HD, 0);
        pack_vt<<<BATCH * NKV * (S_LEN / 64), 256, 0, stream>>>(gout, Vt, 2 * NKV * HD, NKV * HD);

        flash_attn<<<2048, 256, 0, stream>>>(Qr, Kr, Vt, hs_bf);

        conv_f32_bf16<<<(HID * HID / 4 + 255) / 256, 256, 0, stream>>>(o_w, wbuf, HID * HID / 4);
        dim3 go(MROWS / 128, HID / 64);               // (32, 32) = 1024 blocks = 4/CU
        gemm_bt64<<<go, 256, 0, stream>>>(hs_bf, wbuf, out, MROWS, HID, HID);
    }
}